// Round 6
// baseline (14.284 us; speedup 1.0000x reference)
//
#include <hip/hip_runtime.h>
#include <stdint.h>

#define PAGE 16

typedef int v4i __attribute__((ext_vector_type(4)));

// Fused kernel: one block (512 threads = 8 waves) per batch element.
// grid 1024 x 8 waves = 8192 waves = full chip occupancy (4 blocks/CU).
// Each block redundantly computes its exclusive prefix sums (extend tokens,
// new pages) over b' < b via int4-vectorized loads (inputs are 4 KB, L1/L2
// resident broadcast), then writes its output segment with nontemporal int4
// coalesced stores.
__global__ __launch_bounds__(512) void fused_fill(
        const int* __restrict__ pre_lens,
        const int* __restrict__ seq_lens,
        const int* __restrict__ last_loc,
        const int* __restrict__ free_page,
        int* __restrict__ out,
        int B, int n_free) {
    const int b   = blockIdx.x;
    const int tid = threadIdx.x;

    // ---- per-block exclusive prefix over b' < b (int4-vectorized) ----
    int pe = 0, pp = 0;
    const int nv = b >> 2;                    // full int4 groups in [0, b)
    for (int g = tid; g < nv; g += 512) {     // b<=1024 -> single round
        v4i pr = *(const v4i*)(pre_lens + g * 4);
        v4i sq = *(const v4i*)(seq_lens + g * 4);
        #pragma unroll
        for (int j = 0; j < 4; ++j) {
            pe += sq[j] - pr[j];
            pp += ((sq[j] + PAGE - 1) >> 4) - ((pr[j] + PAGE - 1) >> 4);
        }
    }
    for (int i = (nv << 2) + tid; i < b; i += 512) {   // <=3 remainder
        int pre = pre_lens[i];
        int seq = seq_lens[i];
        pe += seq - pre;
        pp += ((seq + PAGE - 1) >> 4) - ((pre + PAGE - 1) >> 4);
    }
    // wave butterfly reduce (64 lanes)
    #pragma unroll
    for (int off = 32; off; off >>= 1) {
        pe += __shfl_xor(pe, off);
        pp += __shfl_xor(pp, off);
    }
    __shared__ int se[8], sp[8];
    const int wave = tid >> 6, lane = tid & 63;
    if (lane == 0) { se[wave] = pe; sp[wave] = pp; }
    __syncthreads();
    int os = 0, ps = 0;
    #pragma unroll
    for (int w = 0; w < 8; ++w) { os += se[w]; ps += sp[w]; }

    // ---- per-sequence parameters ----
    const int pre  = pre_lens[b];
    const int seq  = seq_lens[b];
    const int ext  = seq - pre;
    const int last = last_loc[b];
    const int npb  = (pre + PAGE - 1) >> 4;
    const int boundary = npb * PAGE;     // end of the partial first page
    const int basep    = ps - npb;       // pidx = basep + pos/16

    int* __restrict__ seg = out + os;

    auto val = [&](int t) -> int {
        int pos = pre + t;
        if (pos < boundary) {
            return last + 1 + t;
        }
        // in-range by construction on this branch (ref's clip only guards
        // lanes it discards): pidx in [page_start, page_start + new_pages)
        return free_page[basep + (pos >> 4)] * PAGE + (pos & (PAGE - 1));
    };

    // ---- head peel to 16B alignment ----
    int head = (int)((16u - ((uint32_t)(uintptr_t)seg & 15u)) & 15u) >> 2;
    if (head > ext) head = ext;
    if (tid < head) seg[tid] = val(tid);

    // ---- int4 main body (nontemporal streaming stores) ----
    const int nvec = (ext - head) >> 2;
    for (int v = tid; v < nvec; v += 512) {
        const int t = head + v * 4;
        const int pos = pre + t;
        v4i o;
        if (pos >= boundary) {
            // fully in the paged region: 4 consecutive tokens span <= 2 pages
            const int p0 = free_page[basep + (pos >> 4)] * PAGE;
            const int m0 = pos & 15;
            if (m0 <= 12) {            // all four tokens in one page
                o.x = p0 + m0;
                o.y = p0 + m0 + 1;
                o.z = p0 + m0 + 2;
                o.w = p0 + m0 + 3;
            } else {                   // straddles a page boundary
                const int p1 = free_page[basep + ((pos + 3) >> 4)] * PAGE;
                o.x = p0 + m0;
                o.y = (m0 + 1 <= 15 ? p0 + ((m0 + 1) & 15) : p1 + ((m0 + 1) & 15));
                o.z = (m0 + 2 <= 15 ? p0 + ((m0 + 2) & 15) : p1 + ((m0 + 2) & 15));
                o.w = p1 + ((m0 + 3) & 15);
            }
        } else {
            o.x = val(t);
            o.y = val(t + 1);
            o.z = val(t + 2);
            o.w = val(t + 3);
        }
        __builtin_nontemporal_store(o, (v4i*)(seg + t));
    }

    // ---- tail ----
    for (int t = head + nvec * 4 + tid; t < ext; t += 512) {
        seg[t] = val(t);
    }
}

extern "C" void kernel_launch(void* const* d_in, const int* in_sizes, int n_in,
                              void* d_out, int out_size, void* d_ws, size_t ws_size,
                              hipStream_t stream) {
    const int* pre_lens  = (const int*)d_in[0];
    const int* seq_lens  = (const int*)d_in[1];
    const int* last_loc  = (const int*)d_in[2];
    const int* free_page = (const int*)d_in[3];
    const int B      = in_sizes[0];
    const int n_free = in_sizes[3];
    int* out = (int*)d_out;

    fused_fill<<<B, 512, 0, stream>>>(pre_lens, seq_lens, last_loc, free_page,
                                      out, B, n_free);
}